// Round 1
// baseline (380.281 us; speedup 1.0000x reference)
//
#include <hip/hip_runtime.h>
#include <hip/hip_bf16.h>

#define HID 128
#define NNODES 50000
#define NEDGES 800000
#define NGRAPHS 64
#define BN_EPS 1e-5f
#define CAP 64  // bucket capacity; deg ~ Poisson(16), P(deg>63) ~ 1e-21

typedef __attribute__((ext_vector_type(8))) short short8;   // 8 bf16 (4 VGPRs)
typedef __attribute__((ext_vector_type(4))) float f32x4;    // MFMA acc

static __device__ __forceinline__ unsigned short f2bf(float v) {
  __hip_bfloat16 b = __float2bfloat16(v);  // round-to-nearest
  return *reinterpret_cast<unsigned short*>(&b);
}
static __device__ __forceinline__ float bf2f(unsigned short u) {
  return __uint_as_float(((unsigned)u) << 16);
}

// pack fp32 -> (hi bf16 | lo bf16 << 16) in one u32 (bf16x3 split, done ONCE
// at write time; previously every consuming wave re-split the f32).
static __device__ __forceinline__ unsigned packhl(float v) {
  unsigned short h = f2bf(v);
  unsigned short l = f2bf(v - bf2f(h));
  return (unsigned)h | ((unsigned)l << 16);
}
// reconstruct fp32 from packed (hi + lo), 3 VALU ops
static __device__ __forceinline__ float upk(unsigned p) {
  return __uint_as_float(p << 16) + __uint_as_float(p & 0xFFFF0000u);
}
// 8 packed u32 -> hi/lo short8 fragments (and/or/shift -> v_perm-able)
static __device__ __forceinline__ void unpack8(uint4 wa, uint4 wb,
                                               short8& hi, short8& lo) {
  union U { unsigned u[4]; short8 s; };
  U H, L;
  unsigned w[8] = {wa.x, wa.y, wa.z, wa.w, wb.x, wb.y, wb.z, wb.w};
  #pragma unroll
  for (int t = 0; t < 4; t++) {
    unsigned a = w[2 * t], b = w[2 * t + 1];
    H.u[t] = (a & 0xFFFFu) | (b << 16);
    L.u[t] = (a >> 16) | (b & 0xFFFF0000u);
  }
  hi = H.s; lo = L.s;
}

// ===========================================================================
// prep (single kernel): xbf = bf16(node_emb[x_idx]) + bucket-CSR build +
// weight pack (MFMA B-frag layout, hi/lo split).
// Bucket: pos = atomicAdd(cnt[dst]); eout[dst*CAP+pos] = src|(attr<<16).
// Wpk: hi at idx, lo at idx+65536; idx=(((m*8+t)*4+q)*64+l)*8+j,
// lane l holds W[k=(l>>4)*8+j+q*32][n=t*16+(l&15)], m=layer*2+{0:W1,1:W2}
// ===========================================================================
__global__ __launch_bounds__(256) void prep_kernel(
    const int* __restrict__ x_idx, const float* __restrict__ node_emb,
    unsigned int* __restrict__ xb2, const int* __restrict__ eidx,
    const int* __restrict__ eattr, int* __restrict__ cnt,
    int* __restrict__ eout, const float* __restrict__ W1,
    const float* __restrict__ W2, unsigned short* __restrict__ Wpk) {
  int i = blockIdx.x * 256 + threadIdx.x;
  int stride = gridDim.x * 256;
  const float2* ne2 = (const float2*)node_emb;
  for (int t = i; t < NNODES * (HID / 2); t += stride) {
    int n = t >> 6;  // HID/2 == 64
    int c2 = t & 63;
    float2 v = ne2[x_idx[n] * 64 + c2];
    xb2[t] = (unsigned)f2bf(v.x) | ((unsigned)f2bf(v.y) << 16);
  }
  for (int e = i; e < NEDGES; e += stride) {
    int d = eidx[NEDGES + e];
    int pos = atomicAdd(&cnt[d], 1);
    if (pos < CAP) eout[((size_t)d << 6) + pos] = eidx[e] | (eattr[e] << 16);
  }
  for (int idx = i; idx < 65536; idx += stride) {
    int j = idx & 7;
    int l = (idx >> 3) & 63;
    int q = (idx >> 9) & 3;
    int t = (idx >> 11) & 7;
    int m = idx >> 14;
    int k = ((l >> 4) << 3) + j + (q << 5);
    int n = (t << 4) + (l & 15);
    int layer = m >> 1;
    const float* W = (m & 1) ? W2 : W1;
    float w = W[(size_t)layer * HID * HID + k * HID + n];
    unsigned short h = f2bf(w);
    Wpk[idx] = h;
    Wpk[idx + 65536] = f2bf(w - bf2f(h));
  }
}

// ===========================================================================
// Fused GINE layer. 512 threads (8 waves) per block, NT=32 nodes.
// Gather: wave w owns nodes [w*4, w*4+4), processed NODE-INTERLEAVED: per
// iteration 8 ep-words then 8 x-row gathers (4 nodes x 2 edge quads) are in
// flight, vs the old serial-per-node 2+2. Invalid slots masked by fma(0/1).
// hA is stored PACKED (hi bf16 | lo bf16 <<16) so the split happens once at
// write instead of per consuming wave.
// GEMM: wave w computes ch-tile w (16 channels) x 2 row-tiles via
// mfma_f32_16x16x32_bf16 with hi/lo split (fp32-grade).
// Epilogue: first 256 threads (thread = channel, 16 nodes each).
// ===========================================================================
#define NT 32
#define LDAF 132  // 128+4 u32: 16B-aligned rows, same bank pattern as before
#define GRID_GINE ((NNODES + NT - 1) / NT)  // 1563

__global__ __launch_bounds__(512, 4) void gine_mlp_kernel(
    const unsigned short* __restrict__ in_bf,
    const float* __restrict__ instats,
    const float* __restrict__ gam, const float* __restrict__ bet,
    const int* __restrict__ cnt, const int* __restrict__ eout,
    const float* __restrict__ edge_emb,
    const short8* __restrict__ Wh, const short8* __restrict__ Wl,
    const float* __restrict__ b1, const float* __restrict__ b2,
    unsigned short* __restrict__ out_bf, float* __restrict__ stats,
    const int* __restrict__ batch, float* __restrict__ gpool) {
  __shared__ __align__(16) unsigned hAp[NT * LDAF];  // packed h0->h1->h2
  __shared__ __align__(16) float sheL[4 * HID];  // sh[c] + edge_emb[a][c]

  const int tid = threadIdx.x;
  const int lane = tid & 63;
  const int wave = tid >> 6;   // 0..7
  const int base = blockIdx.x * NT;

  // ---- fill she table (BN shift of previous layer folded into edge emb) ----
  if (tid < 4 * HID) {
    int c = tid & 127;
    float shc = 0.0f;
    if (instats) {
      float mu = instats[c] * (1.0f / NNODES);
      float var = instats[HID + c] * (1.0f / NNODES) - mu * mu;
      float s = gam[c] * rsqrtf(var + BN_EPS);
      shc = bet[c] - mu * s;
    }
    sheL[tid] = shc + edge_emb[tid];
  }

  // ---- per-lane affine over 8 channels (c8*8 .. c8*8+7) ----
  const int c8 = lane & 15;
  const int grp = lane >> 4;
  float scl8[8], sh8[8];
  #pragma unroll
  for (int j = 0; j < 8; j++) { scl8[j] = 1.0f; sh8[j] = 0.0f; }
  if (instats) {
    #pragma unroll
    for (int j = 0; j < 8; j++) {
      int c = c8 * 8 + j;
      float mu = instats[c] * (1.0f / NNODES);
      float var = instats[HID + c] * (1.0f / NNODES) - mu * mu;
      float s = gam[c] * rsqrtf(var + BN_EPS);
      scl8[j] = s;
      sh8[j] = bet[c] - mu * s;
    }
  }
  __syncthreads();  // sheL ready

  // ---- phase 1: gather, node-interleaved (8 gathers in flight/wave) ----
  {
    const short8* in8 = (const short8*)in_bf;  // row = 16 short8s
    int node0 = base + wave * 4;
    const int* ep = eout + ((size_t)node0 << 6);  // 4 rows of 64 ints
    int degs[4];
    #pragma unroll
    for (int i = 0; i < 4; i++) {  // 4 independent loads in flight
      int nd = node0 + i;
      degs[i] = (nd < NNODES) ? min(cnt[nd], CAP) : 0;
    }
    float acc[4][8];
    #pragma unroll
    for (int i = 0; i < 4; i++)
      #pragma unroll
      for (int j = 0; j < 8; j++) acc[i][j] = 0.0f;
    if (grp == 0) {  // self term, 4 independent row loads
      #pragma unroll
      for (int i = 0; i < 4; i++) {
        if (node0 + i < NNODES) {
          short8 s = in8[(node0 + i) * 16 + c8];
          #pragma unroll
          for (int j = 0; j < 8; j++)
            acc[i][j] = fmaf(bf2f((unsigned short)s[j]), scl8[j], sh8[j]);
        }
      }
    }
    int maxdeg = max(max(degs[0], degs[1]), max(degs[2], degs[3]));
    for (int e = 0; e < maxdeg; e += 8) {
      // 8 ep-word loads in flight (wave-uniform predicates; p=0 when dead,
      // masked below -- eout rows are full CAP so over-reads stay in-bounds)
      int pA[4], pB[4];
      #pragma unroll
      for (int i = 0; i < 4; i++) {
        pA[i] = (e < degs[i]) ? ep[i * 64 + e + grp] : 0;
        pB[i] = (e + 4 < degs[i]) ? ep[i * 64 + e + 4 + grp] : 0;
      }
      // 8 x-row gathers in flight
      short8 xA[4], xB[4];
      #pragma unroll
      for (int i = 0; i < 4; i++) xA[i] = in8[(pA[i] & 0xFFFF) * 16 + c8];
      #pragma unroll
      for (int i = 0; i < 4; i++) xB[i] = in8[(pB[i] & 0xFFFF) * 16 + c8];
      #pragma unroll
      for (int i = 0; i < 4; i++) {
        float mA = (e + grp < degs[i]) ? 1.0f : 0.0f;
        float mB = (e + 4 + grp < degs[i]) ? 1.0f : 0.0f;
        const float4* sA4 =
            (const float4*)&sheL[(((pA[i] >> 16) & 3) << 7) + c8 * 8];
        const float4* sB4 =
            (const float4*)&sheL[(((pB[i] >> 16) & 3) << 7) + c8 * 8];
        float4 sA0 = sA4[0], sA1 = sA4[1], sB0 = sB4[0], sB1 = sB4[1];
        #pragma unroll
        for (int j = 0; j < 8; j++) {
          float seA = (j < 4) ? ((const float*)&sA0)[j] : ((const float*)&sA1)[j - 4];
          float seB = (j < 4) ? ((const float*)&sB0)[j] : ((const float*)&sB1)[j - 4];
          float tA = fmaxf(fmaf(bf2f((unsigned short)xA[i][j]), scl8[j], seA), 0.0f);
          float tB = fmaxf(fmaf(bf2f((unsigned short)xB[i][j]), scl8[j], seB), 0.0f);
          acc[i][j] = fmaf(tA, mA, acc[i][j]);
          acc[i][j] = fmaf(tB, mB, acc[i][j]);
        }
      }
    }
    // combine the 4 edge-slot partials, write packed hi/lo
    #pragma unroll
    for (int i = 0; i < 4; i++) {
      #pragma unroll
      for (int j = 0; j < 8; j++) {
        acc[i][j] += __shfl_xor(acc[i][j], 16);
        acc[i][j] += __shfl_xor(acc[i][j], 32);
      }
      if (grp == 0) {
        unsigned pk[8];
        #pragma unroll
        for (int j = 0; j < 8; j++) pk[j] = packhl(acc[i][j]);
        int nrow = wave * 4 + i;
        *(uint4*)&hAp[nrow * LDAF + c8 * 8] = make_uint4(pk[0], pk[1], pk[2], pk[3]);
        *(uint4*)&hAp[nrow * LDAF + c8 * 8 + 4] = make_uint4(pk[4], pk[5], pk[6], pk[7]);
      }
    }
  }
  __syncthreads();

  const int col = lane & 15;
  const int quad = lane >> 4;
  const int rbase = quad * 4;
  const int ch0 = wave * 16 + col;  // this wave's 16-channel tile
  const int aoff = quad * 8;

  // ---- phase 2: GEMM1 (hA @ W1 + b1, relu) -> back into hA ----
  {
    f32x4 a0 = {0.f, 0.f, 0.f, 0.f}, a1 = a0;
    #pragma unroll
    for (int q = 0; q < 4; q++) {
      int f0 = wave * 256 + q * 64 + lane;
      short8 b0h = Wh[f0], b0l = Wl[f0];
      const unsigned* r0 = &hAp[col * LDAF + q * 32 + aoff];
      const unsigned* r1 = &hAp[(16 + col) * LDAF + q * 32 + aoff];
      short8 a0h, a0l, a1h, a1l;
      unpack8(*(const uint4*)r0, *(const uint4*)(r0 + 4), a0h, a0l);
      unpack8(*(const uint4*)r1, *(const uint4*)(r1 + 4), a1h, a1l);
      a0 = __builtin_amdgcn_mfma_f32_16x16x32_bf16(a0h, b0h, a0, 0, 0, 0);
      a0 = __builtin_amdgcn_mfma_f32_16x16x32_bf16(a0l, b0h, a0, 0, 0, 0);
      a0 = __builtin_amdgcn_mfma_f32_16x16x32_bf16(a0h, b0l, a0, 0, 0, 0);
      a1 = __builtin_amdgcn_mfma_f32_16x16x32_bf16(a1h, b0h, a1, 0, 0, 0);
      a1 = __builtin_amdgcn_mfma_f32_16x16x32_bf16(a1l, b0h, a1, 0, 0, 0);
      a1 = __builtin_amdgcn_mfma_f32_16x16x32_bf16(a1h, b0l, a1, 0, 0, 0);
    }
    __syncthreads();  // all GEMM1 reads of hA complete
    float bb0 = b1[ch0];
    #pragma unroll
    for (int r = 0; r < 4; r++) {
      hAp[(rbase + r) * LDAF + ch0] = packhl(fmaxf(a0[r] + bb0, 0.0f));
      hAp[(16 + rbase + r) * LDAF + ch0] = packhl(fmaxf(a1[r] + bb0, 0.0f));
    }
  }
  __syncthreads();

  // ---- phase 3: GEMM2 (h1 @ W2 + b2, relu) -> back into hA ----
  {
    f32x4 a0 = {0.f, 0.f, 0.f, 0.f}, a1 = a0;
    #pragma unroll
    for (int q = 0; q < 4; q++) {
      int f0 = 2048 + wave * 256 + q * 64 + lane;  // gemm2 frags
      short8 b0h = Wh[f0], b0l = Wl[f0];
      const unsigned* r0 = &hAp[col * LDAF + q * 32 + aoff];
      const unsigned* r1 = &hAp[(16 + col) * LDAF + q * 32 + aoff];
      short8 a0h, a0l, a1h, a1l;
      unpack8(*(const uint4*)r0, *(const uint4*)(r0 + 4), a0h, a0l);
      unpack8(*(const uint4*)r1, *(const uint4*)(r1 + 4), a1h, a1l);
      a0 = __builtin_amdgcn_mfma_f32_16x16x32_bf16(a0h, b0h, a0, 0, 0, 0);
      a0 = __builtin_amdgcn_mfma_f32_16x16x32_bf16(a0l, b0h, a0, 0, 0, 0);
      a0 = __builtin_amdgcn_mfma_f32_16x16x32_bf16(a0h, b0l, a0, 0, 0, 0);
      a1 = __builtin_amdgcn_mfma_f32_16x16x32_bf16(a1h, b0h, a1, 0, 0, 0);
      a1 = __builtin_amdgcn_mfma_f32_16x16x32_bf16(a1l, b0h, a1, 0, 0, 0);
      a1 = __builtin_amdgcn_mfma_f32_16x16x32_bf16(a1h, b0l, a1, 0, 0, 0);
    }
    __syncthreads();  // all GEMM2 reads complete
    float bb0 = b2[ch0];
    #pragma unroll
    for (int r = 0; r < 4; r++) {
      hAp[(rbase + r) * LDAF + ch0] = packhl(fmaxf(a0[r] + bb0, 0.0f));
      hAp[(16 + rbase + r) * LDAF + ch0] = packhl(fmaxf(a1[r] + bb0, 0.0f));
    }
  }
  __syncthreads();

  // ---- phase 4: epilogue (h2 packed in hAp); first 256 threads only ----
  if (tid < 256) {
    const int c = tid & 127;
    const int yy = tid >> 7;
    float lsum = 0.0f, lsq = 0.0f;
    if (out_bf) {
      #pragma unroll 4
      for (int i = 0; i < 16; i++) {
        int n = yy * 16 + i;
        int node = base + n;
        if (node < NNODES) {
          unsigned p = hAp[n * LDAF + c];
          out_bf[node * HID + c] = (unsigned short)(p & 0xFFFF);  // == f2bf(v)
          float v = upk(p);
          lsum += v;
          lsq += v * v;
        }
      }
    } else {
      int curg = -1;
      float pacc = 0.0f;
      for (int i = 0; i < 16; i++) {
        int n = yy * 16 + i;
        int node = base + n;
        if (node < NNODES) {
          float v = upk(hAp[n * LDAF + c]);
          lsum += v;
          lsq += v * v;
          int bg = batch[node];
          if (bg != curg) {
            if (curg >= 0) unsafeAtomicAdd(&gpool[curg * HID + c], pacc);
            curg = bg;
            pacc = 0.0f;
          }
          pacc += v;
        }
      }
      if (curg >= 0) unsafeAtomicAdd(&gpool[curg * HID + c], pacc);
    }
    unsafeAtomicAdd(&stats[c], lsum);
    unsafeAtomicAdd(&stats[HID + c], lsq);
  }
}

// ---------------------------------------------------------------------------
// out[g,c] = scl_c * gpool[g,c] + cnt_g * sh_c  (BN affine commutes with pool)
__device__ __forceinline__ int lbound(const int* __restrict__ arr, int n,
                                      int key) {
  int lo = 0, hi = n;
  while (lo < hi) {
    int mid = (lo + hi) >> 1;
    if (arr[mid] < key) lo = mid + 1; else hi = mid;
  }
  return lo;
}

__global__ __launch_bounds__(128) void finish_kernel(
    const float* __restrict__ gpool, const float* __restrict__ stats,
    const float* __restrict__ gam, const float* __restrict__ bet,
    const int* __restrict__ batch, float* __restrict__ out) {
  __shared__ int cnt_s;
  int g = blockIdx.x, c = threadIdx.x;
  if (c == 0)
    cnt_s = lbound(batch, NNODES, g + 1) - lbound(batch, NNODES, g);
  __syncthreads();
  float mu = stats[c] * (1.0f / NNODES);
  float var = stats[HID + c] * (1.0f / NNODES) - mu * mu;
  float scl = gam[c] * rsqrtf(var + BN_EPS);
  float sh = bet[c] - mu * scl;
  out[g * HID + c] = fmaf(gpool[g * HID + c], scl, (float)cnt_s * sh);
}

// ---------------------------------------------------------------------------
extern "C" void kernel_launch(void* const* d_in, const int* in_sizes, int n_in,
                              void* d_out, int out_size, void* d_ws, size_t ws_size,
                              hipStream_t stream) {
  const int* x_idx = (const int*)d_in[0];
  const int* eidx = (const int*)d_in[1];   // [2, E]: src row then dst row
  const int* eattr = (const int*)d_in[2];
  const int* batch = (const int*)d_in[3];
  const float* node_emb = (const float*)d_in[4];
  const float* edge_emb = (const float*)d_in[5];
  const float* W1 = (const float*)d_in[6];
  const float* b1 = (const float*)d_in[7];
  const float* W2 = (const float*)d_in[8];
  const float* b2 = (const float*)d_in[9];
  const float* bn_g = (const float*)d_in[10];
  const float* bn_b = (const float*)d_in[11];
  float* out = (float*)d_out;

  const size_t nfeat = (size_t)NNODES * HID;
  unsigned short* xbf = (unsigned short*)d_ws;  // [N,H] bf16
  unsigned short* h2bf = xbf + nfeat;           // [N,H] bf16
  float* stats0 = (float*)(h2bf + nfeat);       // [2,H]
  float* stats1 = stats0 + 2 * HID;             // [2,H]
  float* gpool = stats1 + 2 * HID;              // [G,H]
  int* cnt = (int*)(gpool + NGRAPHS * HID);     // [N]   (zeroed with stats)
  int* eout = cnt + NNODES;                     // [N*CAP]
  unsigned short* Wpk = (unsigned short*)(eout + (size_t)NNODES * CAP);
  size_t needed = (size_t)((char*)(Wpk + 131072) - (char*)d_ws);
  if (ws_size < needed) return;  // fails validation loudly, doesn't corrupt

  // zero stats0, stats1, gpool, cnt in one shot (contiguous)
  hipMemsetAsync(stats0, 0, (4 * HID + NGRAPHS * HID + NNODES) * sizeof(int),
                 stream);

  prep_kernel<<<1024, 256, 0, stream>>>(x_idx, node_emb, (unsigned int*)xbf,
                                        eidx, eattr, cnt, eout, W1, W2, Wpk);

  const short8* Wfh = (const short8*)Wpk;  // 8192 frags (hi)
  const short8* Wfl = Wfh + 8192;          // 8192 frags (lo)
  // layer 0: in = xbf (identity affine), out -> h2bf, stats0
  gine_mlp_kernel<<<GRID_GINE, 512, 0, stream>>>(
      xbf, nullptr, nullptr, nullptr, cnt, eout, edge_emb,
      Wfh + 0 * 2048, Wfl + 0 * 2048, b1, b2, h2bf, stats0, nullptr, nullptr);
  // layer 1: in = h2bf with BN(layer0) folded, out -> gpool + stats1
  gine_mlp_kernel<<<GRID_GINE, 512, 0, stream>>>(
      h2bf, stats0, bn_g, bn_b, cnt, eout, edge_emb,
      Wfh + 2 * 2048, Wfl + 2 * 2048, b1 + HID, b2 + HID, nullptr, stats1,
      batch, gpool);
  // final: out = scl*gpool + cnt*sh
  finish_kernel<<<NGRAPHS, 128, 0, stream>>>(gpool, stats1, bn_g + HID,
                                             bn_b + HID, batch, out);
}

// Round 2
// 348.890 us; speedup vs baseline: 1.0900x; 1.0900x over previous
//
#include <hip/hip_runtime.h>
#include <hip/hip_bf16.h>

#define HID 128
#define NNODES 50000
#define NEDGES 800000
#define NGRAPHS 64
#define BN_EPS 1e-5f
#define CAP 64  // bucket capacity; deg ~ Poisson(16), P(deg>63) ~ 1e-21

typedef __attribute__((ext_vector_type(8))) short short8;   // 8 bf16 (4 VGPRs)
typedef __attribute__((ext_vector_type(4))) float f32x4;    // MFMA acc

static __device__ __forceinline__ unsigned short f2bf(float v) {
  __hip_bfloat16 b = __float2bfloat16(v);  // round-to-nearest
  return *reinterpret_cast<unsigned short*>(&b);
}
static __device__ __forceinline__ float bf2f(unsigned short u) {
  return __uint_as_float(((unsigned)u) << 16);
}
static __device__ __forceinline__ float lo16f(unsigned u) {
  return __uint_as_float(u << 16);
}
static __device__ __forceinline__ float hi16f(unsigned u) {
  return __uint_as_float(u & 0xFFFF0000u);
}

// pack fp32 -> (hi bf16 | lo bf16 << 16) in one u32 (bf16x3 split, done ONCE
// at write time).
static __device__ __forceinline__ unsigned packhl(float v) {
  unsigned short h = f2bf(v);
  unsigned short l = f2bf(v - bf2f(h));
  return (unsigned)h | ((unsigned)l << 16);
}
// reconstruct fp32 from packed (hi + lo), 3 VALU ops
static __device__ __forceinline__ float upk(unsigned p) {
  return __uint_as_float(p << 16) + __uint_as_float(p & 0xFFFF0000u);
}
// 8 packed u32 -> hi/lo short8 fragments
static __device__ __forceinline__ void unpack8(uint4 wa, uint4 wb,
                                               short8& hi, short8& lo) {
  union U { unsigned u[4]; short8 s; };
  U H, L;
  unsigned w[8] = {wa.x, wa.y, wa.z, wa.w, wb.x, wb.y, wb.z, wb.w};
  #pragma unroll
  for (int t = 0; t < 4; t++) {
    unsigned a = w[2 * t], b = w[2 * t + 1];
    H.u[t] = (a & 0xFFFFu) | (b << 16);
    L.u[t] = (a >> 16) | (b & 0xFFFF0000u);
  }
  hi = H.s; lo = L.s;
}

// ===========================================================================
// prep (single kernel): xbf = bf16(node_emb[x_idx]) + bucket-CSR build +
// weight pack (MFMA B-frag layout, hi/lo split).
// Bucket: pos = atomicAdd(cnt[dst]);
//   eout[dst*CAP+pos] = src | attr<<16 | type<<18   (23 bits used)
//   layer1 reads src = w&0xFFFF, attr = (w>>16)&3;
//   layer0 reads combo = (w>>16)&127 = type*4+attr  (< 76).
// Wpk: hi at idx, lo at idx+65536; idx=(((m*8+t)*4+q)*64+l)*8+j,
// lane l holds W[k=(l>>4)*8+j+q*32][n=t*16+(l&15)], m=layer*2+{0:W1,1:W2}
// ===========================================================================
__global__ __launch_bounds__(256) void prep_kernel(
    const int* __restrict__ x_idx, const float* __restrict__ node_emb,
    unsigned int* __restrict__ xb2, const int* __restrict__ eidx,
    const int* __restrict__ eattr, int* __restrict__ cnt,
    int* __restrict__ eout, const float* __restrict__ W1,
    const float* __restrict__ W2, unsigned short* __restrict__ Wpk) {
  int i = blockIdx.x * 256 + threadIdx.x;
  int stride = gridDim.x * 256;
  const float2* ne2 = (const float2*)node_emb;
  for (int t = i; t < NNODES * (HID / 2); t += stride) {
    int n = t >> 6;  // HID/2 == 64
    int c2 = t & 63;
    float2 v = ne2[x_idx[n] * 64 + c2];
    xb2[t] = (unsigned)f2bf(v.x) | ((unsigned)f2bf(v.y) << 16);
  }
  for (int e = i; e < NEDGES; e += stride) {
    int s = eidx[e];
    int d = eidx[NEDGES + e];
    int ty = x_idx[s];  // 0..18, L2-resident 200KB table
    int pos = atomicAdd(&cnt[d], 1);
    if (pos < CAP)
      eout[((size_t)d << 6) + pos] = s | (eattr[e] << 16) | (ty << 18);
  }
  for (int idx = i; idx < 65536; idx += stride) {
    int j = idx & 7;
    int l = (idx >> 3) & 63;
    int q = (idx >> 9) & 3;
    int t = (idx >> 11) & 7;
    int m = idx >> 14;
    int k = ((l >> 4) << 3) + j + (q << 5);
    int n = (t << 4) + (l & 15);
    int layer = m >> 1;
    const float* W = (m & 1) ? W2 : W1;
    float w = W[(size_t)layer * HID * HID + k * HID + n];
    unsigned short h = f2bf(w);
    Wpk[idx] = h;
    Wpk[idx + 65536] = f2bf(w - bf2f(h));
  }
}

// ===========================================================================
// Fused GINE layer, templated on L0 (layer-0 fast path).
// L0: messages relu(x[src]+e[attr]) take only 19*4=76 distinct values ->
//     precompute msgT[77][128] bf16-packed in LDS (row 76 = zero sentinel);
//     gather = ep-word stream + one ds_read_b128 + 8 f32 adds per edge.
//     NO random global traffic, no affine, no mask-fmas.
// L1: distinct per-node rows -> global gather path (node-interleaved) with
//     folded BN affine (scl/sh) and she = sh + edge_emb table.
// GEMM: wave w computes ch-tile w (16 ch) x 2 row-tiles, 16x16x32 bf16 MFMA,
// hi/lo split (fp32-grade). hA stored packed (hi|lo<<16).
// Epilogue: first 256 threads (thread = channel, 16 nodes each).
// ===========================================================================
#define NT 32
#define LDAF 132    // 128+4 u32: 16B-aligned rows
#define MROW 68     // msgT row stride in u32 (64 + 4 pad: staggers banks)
#define GRID_GINE ((NNODES + NT - 1) / NT)  // 1563

template <bool L0>
__global__ __launch_bounds__(512, 4) void gine_mlp_kernel(
    const unsigned short* __restrict__ in_bf,
    const float* __restrict__ instats,
    const float* __restrict__ gam, const float* __restrict__ bet,
    const int* __restrict__ cnt, const int* __restrict__ eout,
    const float* __restrict__ node_emb, const float* __restrict__ edge_emb,
    const short8* __restrict__ Wh, const short8* __restrict__ Wl,
    const float* __restrict__ b1, const float* __restrict__ b2,
    unsigned short* __restrict__ out_bf, float* __restrict__ stats,
    const int* __restrict__ batch, float* __restrict__ gpool) {
  extern __shared__ __align__(16) char smem[];
  unsigned* hAp = (unsigned*)smem;                       // NT*LDAF packed
  float* sheL = (float*)(smem + NT * LDAF * 4);          // L1: 4*HID
  unsigned* msgT = (unsigned*)(smem + NT * LDAF * 4);    // L0: 77*MROW

  const int tid = threadIdx.x;
  const int lane = tid & 63;
  const int wave = tid >> 6;   // 0..7
  const int base = blockIdx.x * NT;

  const int c8 = lane & 15;
  const int grp = lane >> 4;
  float scl8[8], sh8[8];

  if constexpr (L0) {
    // ---- build message table: relu(node_emb[t] + edge_emb[a]), bf16x2 ----
    for (int t = tid; t < 77 * 64; t += 512) {
      int combo = t >> 6, c2 = (t & 63) << 1;
      unsigned v = 0;
      if (combo < 76) {
        int ty = combo >> 2, at = combo & 3;
        float a0 = fmaxf(node_emb[ty * HID + c2] + edge_emb[at * HID + c2], 0.f);
        float a1 = fmaxf(node_emb[ty * HID + c2 + 1] + edge_emb[at * HID + c2 + 1], 0.f);
        v = (unsigned)f2bf(a0) | ((unsigned)f2bf(a1) << 16);
      }
      msgT[combo * MROW + (t & 63)] = v;
    }
  } else {
    // ---- she table (BN shift of previous layer folded into edge emb) ----
    if (tid < 4 * HID) {
      int c = tid & 127;
      float mu = instats[c] * (1.0f / NNODES);
      float var = instats[HID + c] * (1.0f / NNODES) - mu * mu;
      float s = gam[c] * rsqrtf(var + BN_EPS);
      float shc = bet[c] - mu * s;
      sheL[tid] = shc + edge_emb[tid];
    }
    // ---- per-lane affine over 8 channels (c8*8 .. c8*8+7) ----
    #pragma unroll
    for (int j = 0; j < 8; j++) {
      int c = c8 * 8 + j;
      float mu = instats[c] * (1.0f / NNODES);
      float var = instats[HID + c] * (1.0f / NNODES) - mu * mu;
      float s = gam[c] * rsqrtf(var + BN_EPS);
      scl8[j] = s;
      sh8[j] = bet[c] - mu * s;
    }
  }
  __syncthreads();  // msgT / sheL ready

  // ---- phase 1: gather ----
  {
    const short8* in8 = (const short8*)in_bf;  // row = 16 short8s
    int node0 = base + wave * 4;
    const int* ep = eout + ((size_t)node0 << 6);  // 4 rows of 64 ints
    int degs[4];
    #pragma unroll
    for (int i = 0; i < 4; i++) {
      int nd = node0 + i;
      degs[i] = (nd < NNODES) ? min(cnt[nd], CAP) : 0;
    }
    float acc[4][8];
    #pragma unroll
    for (int i = 0; i < 4; i++)
      #pragma unroll
      for (int j = 0; j < 8; j++) acc[i][j] = 0.0f;
    if (grp == 0) {  // self term
      #pragma unroll
      for (int i = 0; i < 4; i++) {
        if (node0 + i < NNODES) {
          short8 s = in8[(node0 + i) * 16 + c8];
          #pragma unroll
          for (int j = 0; j < 8; j++) {
            if constexpr (L0)
              acc[i][j] = bf2f((unsigned short)s[j]);
            else
              acc[i][j] = fmaf(bf2f((unsigned short)s[j]), scl8[j], sh8[j]);
          }
        }
      }
    }
    int maxdeg = max(max(degs[0], degs[1]), max(degs[2], degs[3]));

    if constexpr (L0) {
      // LDS-table path: per-lane exact predicates; dead slots -> zero row 76
      for (int e = 0; e < maxdeg; e += 8) {
        int pA[4], pB[4];
        #pragma unroll
        for (int i = 0; i < 4; i++) {
          pA[i] = (e + grp < degs[i]) ? ep[i * 64 + e + grp] : (76 << 16);
          pB[i] = (e + 4 + grp < degs[i]) ? ep[i * 64 + e + 4 + grp] : (76 << 16);
        }
        #pragma unroll
        for (int i = 0; i < 4; i++) {
          uint4 va = *(const uint4*)&msgT[((pA[i] >> 16) & 127) * MROW + (c8 << 2)];
          uint4 vb = *(const uint4*)&msgT[((pB[i] >> 16) & 127) * MROW + (c8 << 2)];
          acc[i][0] += lo16f(va.x) + lo16f(vb.x);
          acc[i][1] += hi16f(va.x) + hi16f(vb.x);
          acc[i][2] += lo16f(va.y) + lo16f(vb.y);
          acc[i][3] += hi16f(va.y) + hi16f(vb.y);
          acc[i][4] += lo16f(va.z) + lo16f(vb.z);
          acc[i][5] += hi16f(va.z) + hi16f(vb.z);
          acc[i][6] += lo16f(va.w) + lo16f(vb.w);
          acc[i][7] += hi16f(va.w) + hi16f(vb.w);
        }
      }
    } else {
      // global gather path (node-interleaved, mask-fma)
      for (int e = 0; e < maxdeg; e += 8) {
        int pA[4], pB[4];
        #pragma unroll
        for (int i = 0; i < 4; i++) {
          pA[i] = (e < degs[i]) ? ep[i * 64 + e + grp] : 0;
          pB[i] = (e + 4 < degs[i]) ? ep[i * 64 + e + 4 + grp] : 0;
        }
        short8 xA[4], xB[4];
        #pragma unroll
        for (int i = 0; i < 4; i++) xA[i] = in8[(pA[i] & 0xFFFF) * 16 + c8];
        #pragma unroll
        for (int i = 0; i < 4; i++) xB[i] = in8[(pB[i] & 0xFFFF) * 16 + c8];
        #pragma unroll
        for (int i = 0; i < 4; i++) {
          float mA = (e + grp < degs[i]) ? 1.0f : 0.0f;
          float mB = (e + 4 + grp < degs[i]) ? 1.0f : 0.0f;
          const float4* sA4 =
              (const float4*)&sheL[(((pA[i] >> 16) & 3) << 7) + c8 * 8];
          const float4* sB4 =
              (const float4*)&sheL[(((pB[i] >> 16) & 3) << 7) + c8 * 8];
          float4 sA0 = sA4[0], sA1 = sA4[1], sB0 = sB4[0], sB1 = sB4[1];
          #pragma unroll
          for (int j = 0; j < 8; j++) {
            float seA = (j < 4) ? ((const float*)&sA0)[j] : ((const float*)&sA1)[j - 4];
            float seB = (j < 4) ? ((const float*)&sB0)[j] : ((const float*)&sB1)[j - 4];
            float tA = fmaxf(fmaf(bf2f((unsigned short)xA[i][j]), scl8[j], seA), 0.0f);
            float tB = fmaxf(fmaf(bf2f((unsigned short)xB[i][j]), scl8[j], seB), 0.0f);
            acc[i][j] = fmaf(tA, mA, acc[i][j]);
            acc[i][j] = fmaf(tB, mB, acc[i][j]);
          }
        }
      }
    }

    // combine the 4 edge-slot partials, write packed hi/lo
    #pragma unroll
    for (int i = 0; i < 4; i++) {
      #pragma unroll
      for (int j = 0; j < 8; j++) {
        acc[i][j] += __shfl_xor(acc[i][j], 16);
        acc[i][j] += __shfl_xor(acc[i][j], 32);
      }
      if (grp == 0) {
        unsigned pk[8];
        #pragma unroll
        for (int j = 0; j < 8; j++) pk[j] = packhl(acc[i][j]);
        int nrow = wave * 4 + i;
        *(uint4*)&hAp[nrow * LDAF + c8 * 8] = make_uint4(pk[0], pk[1], pk[2], pk[3]);
        *(uint4*)&hAp[nrow * LDAF + c8 * 8 + 4] = make_uint4(pk[4], pk[5], pk[6], pk[7]);
      }
    }
  }
  __syncthreads();

  const int col = lane & 15;
  const int quad = lane >> 4;
  const int rbase = quad * 4;
  const int ch0 = wave * 16 + col;  // this wave's 16-channel tile
  const int aoff = quad * 8;

  // ---- phase 2: GEMM1 (hA @ W1 + b1, relu) -> back into hA ----
  {
    f32x4 a0 = {0.f, 0.f, 0.f, 0.f}, a1 = a0;
    #pragma unroll
    for (int q = 0; q < 4; q++) {
      int f0 = wave * 256 + q * 64 + lane;
      short8 b0h = Wh[f0], b0l = Wl[f0];
      const unsigned* r0 = &hAp[col * LDAF + q * 32 + aoff];
      const unsigned* r1 = &hAp[(16 + col) * LDAF + q * 32 + aoff];
      short8 a0h, a0l, a1h, a1l;
      unpack8(*(const uint4*)r0, *(const uint4*)(r0 + 4), a0h, a0l);
      unpack8(*(const uint4*)r1, *(const uint4*)(r1 + 4), a1h, a1l);
      a0 = __builtin_amdgcn_mfma_f32_16x16x32_bf16(a0h, b0h, a0, 0, 0, 0);
      a0 = __builtin_amdgcn_mfma_f32_16x16x32_bf16(a0l, b0h, a0, 0, 0, 0);
      a0 = __builtin_amdgcn_mfma_f32_16x16x32_bf16(a0h, b0l, a0, 0, 0, 0);
      a1 = __builtin_amdgcn_mfma_f32_16x16x32_bf16(a1h, b0h, a1, 0, 0, 0);
      a1 = __builtin_amdgcn_mfma_f32_16x16x32_bf16(a1l, b0h, a1, 0, 0, 0);
      a1 = __builtin_amdgcn_mfma_f32_16x16x32_bf16(a1h, b0l, a1, 0, 0, 0);
    }
    __syncthreads();  // all GEMM1 reads of hA complete
    float bb0 = b1[ch0];
    #pragma unroll
    for (int r = 0; r < 4; r++) {
      hAp[(rbase + r) * LDAF + ch0] = packhl(fmaxf(a0[r] + bb0, 0.0f));
      hAp[(16 + rbase + r) * LDAF + ch0] = packhl(fmaxf(a1[r] + bb0, 0.0f));
    }
  }
  __syncthreads();

  // ---- phase 3: GEMM2 (h1 @ W2 + b2, relu) -> back into hA ----
  {
    f32x4 a0 = {0.f, 0.f, 0.f, 0.f}, a1 = a0;
    #pragma unroll
    for (int q = 0; q < 4; q++) {
      int f0 = 2048 + wave * 256 + q * 64 + lane;  // gemm2 frags
      short8 b0h = Wh[f0], b0l = Wl[f0];
      const unsigned* r0 = &hAp[col * LDAF + q * 32 + aoff];
      const unsigned* r1 = &hAp[(16 + col) * LDAF + q * 32 + aoff];
      short8 a0h, a0l, a1h, a1l;
      unpack8(*(const uint4*)r0, *(const uint4*)(r0 + 4), a0h, a0l);
      unpack8(*(const uint4*)r1, *(const uint4*)(r1 + 4), a1h, a1l);
      a0 = __builtin_amdgcn_mfma_f32_16x16x32_bf16(a0h, b0h, a0, 0, 0, 0);
      a0 = __builtin_amdgcn_mfma_f32_16x16x32_bf16(a0l, b0h, a0, 0, 0, 0);
      a0 = __builtin_amdgcn_mfma_f32_16x16x32_bf16(a0h, b0l, a0, 0, 0, 0);
      a1 = __builtin_amdgcn_mfma_f32_16x16x32_bf16(a1h, b0h, a1, 0, 0, 0);
      a1 = __builtin_amdgcn_mfma_f32_16x16x32_bf16(a1l, b0h, a1, 0, 0, 0);
      a1 = __builtin_amdgcn_mfma_f32_16x16x32_bf16(a1h, b0l, a1, 0, 0, 0);
    }
    __syncthreads();  // all GEMM2 reads complete
    float bb0 = b2[ch0];
    #pragma unroll
    for (int r = 0; r < 4; r++) {
      hAp[(rbase + r) * LDAF + ch0] = packhl(fmaxf(a0[r] + bb0, 0.0f));
      hAp[(16 + rbase + r) * LDAF + ch0] = packhl(fmaxf(a1[r] + bb0, 0.0f));
    }
  }
  __syncthreads();

  // ---- phase 4: epilogue (h2 packed in hAp); first 256 threads only ----
  if (tid < 256) {
    const int c = tid & 127;
    const int yy = tid >> 7;
    float lsum = 0.0f, lsq = 0.0f;
    if (out_bf) {
      #pragma unroll 4
      for (int i = 0; i < 16; i++) {
        int n = yy * 16 + i;
        int node = base + n;
        if (node < NNODES) {
          unsigned p = hAp[n * LDAF + c];
          out_bf[node * HID + c] = (unsigned short)(p & 0xFFFF);  // == f2bf(v)
          float v = upk(p);
          lsum += v;
          lsq += v * v;
        }
      }
    } else {
      int curg = -1;
      float pacc = 0.0f;
      for (int i = 0; i < 16; i++) {
        int n = yy * 16 + i;
        int node = base + n;
        if (node < NNODES) {
          float v = upk(hAp[n * LDAF + c]);
          lsum += v;
          lsq += v * v;
          int bg = batch[node];
          if (bg != curg) {
            if (curg >= 0) unsafeAtomicAdd(&gpool[curg * HID + c], pacc);
            curg = bg;
            pacc = 0.0f;
          }
          pacc += v;
        }
      }
      if (curg >= 0) unsafeAtomicAdd(&gpool[curg * HID + c], pacc);
    }
    unsafeAtomicAdd(&stats[c], lsum);
    unsafeAtomicAdd(&stats[HID + c], lsq);
  }
}

// ---------------------------------------------------------------------------
// out[g,c] = scl_c * gpool[g,c] + cnt_g * sh_c  (BN affine commutes with pool)
__device__ __forceinline__ int lbound(const int* __restrict__ arr, int n,
                                      int key) {
  int lo = 0, hi = n;
  while (lo < hi) {
    int mid = (lo + hi) >> 1;
    if (arr[mid] < key) lo = mid + 1; else hi = mid;
  }
  return lo;
}

__global__ __launch_bounds__(128) void finish_kernel(
    const float* __restrict__ gpool, const float* __restrict__ stats,
    const float* __restrict__ gam, const float* __restrict__ bet,
    const int* __restrict__ batch, float* __restrict__ out) {
  __shared__ int cnt_s;
  int g = blockIdx.x, c = threadIdx.x;
  if (c == 0)
    cnt_s = lbound(batch, NNODES, g + 1) - lbound(batch, NNODES, g);
  __syncthreads();
  float mu = stats[c] * (1.0f / NNODES);
  float var = stats[HID + c] * (1.0f / NNODES) - mu * mu;
  float scl = gam[c] * rsqrtf(var + BN_EPS);
  float sh = bet[c] - mu * scl;
  out[g * HID + c] = fmaf(gpool[g * HID + c], scl, (float)cnt_s * sh);
}

// ---------------------------------------------------------------------------
extern "C" void kernel_launch(void* const* d_in, const int* in_sizes, int n_in,
                              void* d_out, int out_size, void* d_ws, size_t ws_size,
                              hipStream_t stream) {
  const int* x_idx = (const int*)d_in[0];
  const int* eidx = (const int*)d_in[1];   // [2, E]: src row then dst row
  const int* eattr = (const int*)d_in[2];
  const int* batch = (const int*)d_in[3];
  const float* node_emb = (const float*)d_in[4];
  const float* edge_emb = (const float*)d_in[5];
  const float* W1 = (const float*)d_in[6];
  const float* b1 = (const float*)d_in[7];
  const float* W2 = (const float*)d_in[8];
  const float* b2 = (const float*)d_in[9];
  const float* bn_g = (const float*)d_in[10];
  const float* bn_b = (const float*)d_in[11];
  float* out = (float*)d_out;

  const size_t nfeat = (size_t)NNODES * HID;
  unsigned short* xbf = (unsigned short*)d_ws;  // [N,H] bf16
  unsigned short* h2bf = xbf + nfeat;           // [N,H] bf16
  float* stats0 = (float*)(h2bf + nfeat);       // [2,H]
  float* stats1 = stats0 + 2 * HID;             // [2,H]
  float* gpool = stats1 + 2 * HID;              // [G,H]
  int* cnt = (int*)(gpool + NGRAPHS * HID);     // [N]   (zeroed with stats)
  int* eout = cnt + NNODES;                     // [N*CAP]
  unsigned short* Wpk = (unsigned short*)(eout + (size_t)NNODES * CAP);
  size_t needed = (size_t)((char*)(Wpk + 131072) - (char*)d_ws);
  if (ws_size < needed) return;  // fails validation loudly, doesn't corrupt

  // zero stats0, stats1, gpool, cnt in one shot (contiguous)
  hipMemsetAsync(stats0, 0, (4 * HID + NGRAPHS * HID + NNODES) * sizeof(int),
                 stream);

  prep_kernel<<<1024, 256, 0, stream>>>(x_idx, node_emb, (unsigned int*)xbf,
                                        eidx, eattr, cnt, eout, W1, W2, Wpk);

  const short8* Wfh = (const short8*)Wpk;  // 8192 frags (hi)
  const short8* Wfl = Wfh + 8192;          // 8192 frags (lo)
  const size_t smem0 = (size_t)NT * LDAF * 4 + 77 * MROW * 4;  // hAp + msgT
  const size_t smem1 = (size_t)NT * LDAF * 4 + 4 * HID * 4;    // hAp + sheL
  // layer 0: in = xbf, msg-table fast path, out -> h2bf, stats0
  gine_mlp_kernel<true><<<GRID_GINE, 512, smem0, stream>>>(
      xbf, nullptr, nullptr, nullptr, cnt, eout, node_emb, edge_emb,
      Wfh + 0 * 2048, Wfl + 0 * 2048, b1, b2, h2bf, stats0, nullptr, nullptr);
  // layer 1: in = h2bf with BN(layer0) folded, out -> gpool + stats1
  gine_mlp_kernel<false><<<GRID_GINE, 512, smem1, stream>>>(
      h2bf, stats0, bn_g, bn_b, cnt, eout, node_emb, edge_emb,
      Wfh + 2 * 2048, Wfl + 2 * 2048, b1 + HID, b2 + HID, nullptr, stats1,
      batch, gpool);
  // final: out = scl*gpool + cnt*sh
  finish_kernel<<<NGRAPHS, 128, 0, stream>>>(gpool, stats1, bn_g + HID,
                                             bn_b + HID, batch, out);
}

// Round 3
// 293.057 us; speedup vs baseline: 1.2976x; 1.1905x over previous
//
#include <hip/hip_runtime.h>
#include <hip/hip_bf16.h>

#define HID 128
#define NNODES 50000
#define NEDGES 800000
#define NGRAPHS 64
#define BN_EPS 1e-5f
#define CAP 64  // bucket capacity; deg ~ Poisson(16), P(deg>63) ~ 1e-21

typedef __attribute__((ext_vector_type(8))) short short8;   // 8 bf16 (4 VGPRs)
typedef __attribute__((ext_vector_type(4))) float f32x4;    // MFMA acc

static __device__ __forceinline__ unsigned short f2bf(float v) {
  __hip_bfloat16 b = __float2bfloat16(v);  // round-to-nearest
  return *reinterpret_cast<unsigned short*>(&b);
}
static __device__ __forceinline__ float bf2f(unsigned short u) {
  return __uint_as_float(((unsigned)u) << 16);
}
static __device__ __forceinline__ float lo16f(unsigned u) {
  return __uint_as_float(u << 16);
}
static __device__ __forceinline__ float hi16f(unsigned u) {
  return __uint_as_float(u & 0xFFFF0000u);
}

// pack fp32 -> (hi bf16 | lo bf16 << 16) in one u32 (bf16x3 split)
static __device__ __forceinline__ unsigned packhl(float v) {
  unsigned short h = f2bf(v);
  unsigned short l = f2bf(v - bf2f(h));
  return (unsigned)h | ((unsigned)l << 16);
}
// reconstruct fp32 from packed (hi + lo)
static __device__ __forceinline__ float upk(unsigned p) {
  return __uint_as_float(p << 16) + __uint_as_float(p & 0xFFFF0000u);
}
// 8 packed u32 -> hi/lo short8 fragments
static __device__ __forceinline__ void unpack8(uint4 wa, uint4 wb,
                                               short8& hi, short8& lo) {
  union U { unsigned u[4]; short8 s; };
  U H, L;
  unsigned w[8] = {wa.x, wa.y, wa.z, wa.w, wb.x, wb.y, wb.z, wb.w};
  #pragma unroll
  for (int t = 0; t < 4; t++) {
    unsigned a = w[2 * t], b = w[2 * t + 1];
    H.u[t] = (a & 0xFFFFu) | (b << 16);
    L.u[t] = (a >> 16) | (b & 0xFFFF0000u);
  }
  hi = H.s; lo = L.s;
}

// ===========================================================================
// prep: xbf = bf16(node_emb[x_idx]) + bucket-CSR build + weight pack.
//   eout[dst*CAP+pos] = src | attr<<16 | type<<18   (23 bits used)
// ===========================================================================
__global__ __launch_bounds__(256) void prep_kernel(
    const int* __restrict__ x_idx, const float* __restrict__ node_emb,
    unsigned int* __restrict__ xb2, const int* __restrict__ eidx,
    const int* __restrict__ eattr, int* __restrict__ cnt,
    int* __restrict__ eout, const float* __restrict__ W1,
    const float* __restrict__ W2, unsigned short* __restrict__ Wpk) {
  int i = blockIdx.x * 256 + threadIdx.x;
  int stride = gridDim.x * 256;
  const float2* ne2 = (const float2*)node_emb;
  for (int t = i; t < NNODES * (HID / 2); t += stride) {
    int n = t >> 6;  // HID/2 == 64
    int c2 = t & 63;
    float2 v = ne2[x_idx[n] * 64 + c2];
    xb2[t] = (unsigned)f2bf(v.x) | ((unsigned)f2bf(v.y) << 16);
  }
  for (int e = i; e < NEDGES; e += stride) {
    int s = eidx[e];
    int d = eidx[NEDGES + e];
    int ty = x_idx[s];  // 0..18, L2-resident table
    int pos = atomicAdd(&cnt[d], 1);
    if (pos < CAP)
      eout[((size_t)d << 6) + pos] = s | (eattr[e] << 16) | (ty << 18);
  }
  for (int idx = i; idx < 65536; idx += stride) {
    int j = idx & 7;
    int l = (idx >> 3) & 63;
    int q = (idx >> 9) & 3;
    int t = (idx >> 11) & 7;
    int m = idx >> 14;
    int k = ((l >> 4) << 3) + j + (q << 5);
    int n = (t << 4) + (l & 15);
    int layer = m >> 1;
    const float* W = (m & 1) ? W2 : W1;
    float w = W[(size_t)layer * HID * HID + k * HID + n];
    unsigned short h = f2bf(w);
    Wpk[idx] = h;
    Wpk[idx + 65536] = f2bf(w - bf2f(h));
  }
}

// ===========================================================================
// Fused GINE layer, templated on L0.
// Gather (NEW): one edge row = whole wave (64 lanes x 4B = 256B row; lane
// owns channels 2*lane, 2*lane+1). Edge words broadcast from one ep-row
// dword load via readlane (SGPR). L1: explicit 2-strip x 8-edge software
// pipeline -> 16 rows (16 VGPR) in flight per wave, breaking the
// outstanding-load-slot limit that capped R1/R2 at ~1.8 TB/s.
// L0: msgT LDS table (76 distinct messages), one ds_read_b32 per edge.
// No shfl reduction, no mask-fmas, exactly deg edges per node.
// GEMM / epilogue: unchanged (hAp packed hi|lo<<16, 16x16x32 MFMA, hi/lo
// split). Epilogue stats atomics halved via LDS partial combine.
// ===========================================================================
#define NT 32
#define LDAF 132    // 128+4 u32: 16B-aligned rows
#define MROW 68     // msgT row stride in u32 (64 + 4 pad)
#define GRID_GINE ((NNODES + NT - 1) / NT)  // 1563

template <bool L0>
__global__ __launch_bounds__(512, 4) void gine_mlp_kernel(
    const unsigned short* __restrict__ in_bf,
    const float* __restrict__ instats,
    const float* __restrict__ gam, const float* __restrict__ bet,
    const int* __restrict__ cnt, const int* __restrict__ eout,
    const float* __restrict__ node_emb, const float* __restrict__ edge_emb,
    const short8* __restrict__ Wh, const short8* __restrict__ Wl,
    const float* __restrict__ b1, const float* __restrict__ b2,
    unsigned short* __restrict__ out_bf, float* __restrict__ stats,
    const int* __restrict__ batch, float* __restrict__ gpool) {
  extern __shared__ __align__(16) char smem[];
  unsigned* hAp = (unsigned*)smem;                       // NT*LDAF packed
  float* sheL = (float*)(smem + NT * LDAF * 4);          // L1: 4*HID f32
  unsigned* msgT = (unsigned*)(smem + NT * LDAF * 4);    // L0: 77*MROW
  float* red = (float*)(smem + NT * LDAF * 4);           // epilogue scratch

  const int tid = threadIdx.x;
  const int lane = tid & 63;
  const int wave = tid >> 6;   // 0..7
  const int base = blockIdx.x * NT;

  float scl_lo = 1.0f, scl_hi = 1.0f, sh_lo = 0.0f, sh_hi = 0.0f;

  if constexpr (L0) {
    // ---- message table: relu(node_emb[t] + edge_emb[a]), bf16x2 ----
    for (int t = tid; t < 77 * 64; t += 512) {
      int combo = t >> 6, c2 = (t & 63) << 1;
      unsigned v = 0;
      if (combo < 76) {
        int ty = combo >> 2, at = combo & 3;
        float a0 = fmaxf(node_emb[ty * HID + c2] + edge_emb[at * HID + c2], 0.f);
        float a1 = fmaxf(node_emb[ty * HID + c2 + 1] + edge_emb[at * HID + c2 + 1], 0.f);
        v = (unsigned)f2bf(a0) | ((unsigned)f2bf(a1) << 16);
      }
      msgT[combo * MROW + (t & 63)] = v;
    }
  } else {
    // ---- she table (BN shift of previous layer folded into edge emb) ----
    if (tid < 4 * HID) {
      int c = tid & 127;
      float mu = instats[c] * (1.0f / NNODES);
      float var = instats[HID + c] * (1.0f / NNODES) - mu * mu;
      float s = gam[c] * rsqrtf(var + BN_EPS);
      float shc = bet[c] - mu * s;
      sheL[tid] = shc + edge_emb[tid];
    }
    // ---- per-lane affine for channels 2*lane, 2*lane+1 ----
    {
      int c0 = lane << 1;
      float mu0 = instats[c0] * (1.0f / NNODES);
      float var0 = instats[HID + c0] * (1.0f / NNODES) - mu0 * mu0;
      scl_lo = gam[c0] * rsqrtf(var0 + BN_EPS);
      sh_lo = bet[c0] - mu0 * scl_lo;
      float mu1 = instats[c0 + 1] * (1.0f / NNODES);
      float var1 = instats[HID + c0 + 1] * (1.0f / NNODES) - mu1 * mu1;
      scl_hi = gam[c0 + 1] * rsqrtf(var1 + BN_EPS);
      sh_hi = bet[c0 + 1] - mu1 * scl_hi;
    }
  }
  __syncthreads();  // msgT / sheL ready

  // ---- phase 1: gather (wave-per-edge-row) ----
  {
    const unsigned* in4 = (const unsigned*)in_bf;  // row = 64 u32
    int node0 = base + wave * 4;
    float acc0[4], acc1[4];
    #pragma unroll
    for (int i = 0; i < 4; i++) { acc0[i] = 0.0f; acc1[i] = 0.0f; }

    // hoisted: deg (SGPR), ep row, self row for all 4 nodes (12 loads issue)
    int dg4[4], epw4[4];
    unsigned sv4[4];
    #pragma unroll
    for (int i = 0; i < 4; i++) {
      int node = node0 + i;
      bool v = node < NNODES;
      dg4[i] = v ? __builtin_amdgcn_readfirstlane(min(cnt[node], CAP)) : 0;
      epw4[i] = v ? eout[(node << 6) + lane] : 0;
      sv4[i] = v ? in4[(node << 6) + lane] : 0u;
    }

#define GL_ISSUE(SB, X, A)                                      \
    {                                                           \
      _Pragma("unroll")                                         \
      for (int jj = 0; jj < 8; jj++) {                          \
        if ((SB) + jj < dg) {                                   \
          int w = __builtin_amdgcn_readlane(epw, (SB) + jj);    \
          A[jj] = (w >> 16) & 3;                                \
          X[jj] = in4[((w & 0xFFFF) << 6) + lane];              \
        }                                                       \
      }                                                         \
    }
#define GL_CONS(SB, X, A)                                       \
    {                                                           \
      _Pragma("unroll")                                         \
      for (int jj = 0; jj < 8; jj++) {                          \
        if ((SB) + jj < dg) {                                   \
          float e0 = sheL[(A[jj] << 7) + (lane << 1)];          \
          float e1 = sheL[(A[jj] << 7) + (lane << 1) + 1];      \
          acc0[i] += fmaxf(fmaf(lo16f(X[jj]), scl_lo, e0), 0.0f); \
          acc1[i] += fmaxf(fmaf(hi16f(X[jj]), scl_hi, e1), 0.0f); \
        }                                                       \
      }                                                         \
    }

    #pragma unroll
    for (int i = 0; i < 4; i++) {
      int node = node0 + i;
      if (node >= NNODES) continue;  // uniform
      int dg = dg4[i];
      int epw = epw4[i];
      // self term
      if constexpr (L0) {
        acc0[i] = lo16f(sv4[i]);
        acc1[i] = hi16f(sv4[i]);
      } else {
        acc0[i] = fmaf(lo16f(sv4[i]), scl_lo, sh_lo);
        acc1[i] = fmaf(hi16f(sv4[i]), scl_hi, sh_hi);
      }
      if constexpr (L0) {
        // LDS table path: 1 ds_read_b32 + 2 adds per edge
        #pragma unroll 2
        for (int j = 0; j < dg; j++) {
          int w = __builtin_amdgcn_readlane(epw, j);
          unsigned m = msgT[(((w >> 16) & 127) * MROW) + lane];
          acc0[i] += lo16f(m);
          acc1[i] += hi16f(m);
        }
      } else {
        if (dg > 0) {
          // 2-strip software pipeline: 16 rows in flight (16 VGPR)
          unsigned X0[8], X1[8];
          int A0[8], A1[8];
          GL_ISSUE(0, X0, A0);
          int s = 0;
          for (;;) {
            if (s * 8 + 8 < dg) GL_ISSUE(s * 8 + 8, X1, A1);
            GL_CONS(s * 8, X0, A0);
            s++;
            if (s * 8 >= dg) break;
            if (s * 8 + 8 < dg) GL_ISSUE(s * 8 + 8, X0, A0);
            GL_CONS(s * 8, X1, A1);
            s++;
            if (s * 8 >= dg) break;
          }
        }
      }
    }
#undef GL_ISSUE
#undef GL_CONS

    // write packed hi/lo rows (zeros for OOB rows -> GEMM reads no garbage)
    #pragma unroll
    for (int i = 0; i < 4; i++) {
      int nrow = wave * 4 + i;
      hAp[nrow * LDAF + (lane << 1)] = packhl(acc0[i]);
      hAp[nrow * LDAF + (lane << 1) + 1] = packhl(acc1[i]);
    }
  }
  __syncthreads();

  const int col = lane & 15;
  const int quad = lane >> 4;
  const int rbase = quad * 4;
  const int ch0 = wave * 16 + col;  // this wave's 16-channel tile
  const int aoff = quad * 8;

  // ---- phase 2: GEMM1 (hA @ W1 + b1, relu) -> back into hA ----
  {
    f32x4 a0 = {0.f, 0.f, 0.f, 0.f}, a1 = a0;
    #pragma unroll
    for (int q = 0; q < 4; q++) {
      int f0 = wave * 256 + q * 64 + lane;
      short8 b0h = Wh[f0], b0l = Wl[f0];
      const unsigned* r0 = &hAp[col * LDAF + q * 32 + aoff];
      const unsigned* r1 = &hAp[(16 + col) * LDAF + q * 32 + aoff];
      short8 a0h, a0l, a1h, a1l;
      unpack8(*(const uint4*)r0, *(const uint4*)(r0 + 4), a0h, a0l);
      unpack8(*(const uint4*)r1, *(const uint4*)(r1 + 4), a1h, a1l);
      a0 = __builtin_amdgcn_mfma_f32_16x16x32_bf16(a0h, b0h, a0, 0, 0, 0);
      a0 = __builtin_amdgcn_mfma_f32_16x16x32_bf16(a0l, b0h, a0, 0, 0, 0);
      a0 = __builtin_amdgcn_mfma_f32_16x16x32_bf16(a0h, b0l, a0, 0, 0, 0);
      a1 = __builtin_amdgcn_mfma_f32_16x16x32_bf16(a1h, b0h, a1, 0, 0, 0);
      a1 = __builtin_amdgcn_mfma_f32_16x16x32_bf16(a1l, b0h, a1, 0, 0, 0);
      a1 = __builtin_amdgcn_mfma_f32_16x16x32_bf16(a1h, b0l, a1, 0, 0, 0);
    }
    __syncthreads();  // all GEMM1 reads of hA complete
    float bb0 = b1[ch0];
    #pragma unroll
    for (int r = 0; r < 4; r++) {
      hAp[(rbase + r) * LDAF + ch0] = packhl(fmaxf(a0[r] + bb0, 0.0f));
      hAp[(16 + rbase + r) * LDAF + ch0] = packhl(fmaxf(a1[r] + bb0, 0.0f));
    }
  }
  __syncthreads();

  // ---- phase 3: GEMM2 (h1 @ W2 + b2, relu) -> back into hA ----
  {
    f32x4 a0 = {0.f, 0.f, 0.f, 0.f}, a1 = a0;
    #pragma unroll
    for (int q = 0; q < 4; q++) {
      int f0 = 2048 + wave * 256 + q * 64 + lane;  // gemm2 frags
      short8 b0h = Wh[f0], b0l = Wl[f0];
      const unsigned* r0 = &hAp[col * LDAF + q * 32 + aoff];
      const unsigned* r1 = &hAp[(16 + col) * LDAF + q * 32 + aoff];
      short8 a0h, a0l, a1h, a1l;
      unpack8(*(const uint4*)r0, *(const uint4*)(r0 + 4), a0h, a0l);
      unpack8(*(const uint4*)r1, *(const uint4*)(r1 + 4), a1h, a1l);
      a0 = __builtin_amdgcn_mfma_f32_16x16x32_bf16(a0h, b0h, a0, 0, 0, 0);
      a0 = __builtin_amdgcn_mfma_f32_16x16x32_bf16(a0l, b0h, a0, 0, 0, 0);
      a0 = __builtin_amdgcn_mfma_f32_16x16x32_bf16(a0h, b0l, a0, 0, 0, 0);
      a1 = __builtin_amdgcn_mfma_f32_16x16x32_bf16(a1h, b0h, a1, 0, 0, 0);
      a1 = __builtin_amdgcn_mfma_f32_16x16x32_bf16(a1l, b0h, a1, 0, 0, 0);
      a1 = __builtin_amdgcn_mfma_f32_16x16x32_bf16(a1h, b0l, a1, 0, 0, 0);
    }
    __syncthreads();  // all GEMM2 reads complete
    float bb0 = b2[ch0];
    #pragma unroll
    for (int r = 0; r < 4; r++) {
      hAp[(rbase + r) * LDAF + ch0] = packhl(fmaxf(a0[r] + bb0, 0.0f));
      hAp[(16 + rbase + r) * LDAF + ch0] = packhl(fmaxf(a1[r] + bb0, 0.0f));
    }
  }
  __syncthreads();

  // ---- phase 4: epilogue (h2 packed in hAp); first 256 threads compute ----
  float lsum = 0.0f, lsq = 0.0f;
  if (tid < 256) {
    const int c = tid & 127;
    const int yy = tid >> 7;
    if (out_bf) {
      #pragma unroll 4
      for (int i = 0; i < 16; i++) {
        int n = yy * 16 + i;
        int node = base + n;
        if (node < NNODES) {
          unsigned p = hAp[n * LDAF + c];
          out_bf[node * HID + c] = (unsigned short)(p & 0xFFFF);  // == f2bf(v)
          float v = upk(p);
          lsum += v;
          lsq += v * v;
        }
      }
    } else {
      int curg = -1;
      float pacc = 0.0f;
      for (int i = 0; i < 16; i++) {
        int n = yy * 16 + i;
        int node = base + n;
        if (node < NNODES) {
          float v = upk(hAp[n * LDAF + c]);
          lsum += v;
          lsq += v * v;
          int bg = batch[node];
          if (bg != curg) {
            if (curg >= 0) unsafeAtomicAdd(&gpool[curg * HID + c], pacc);
            curg = bg;
            pacc = 0.0f;
          }
          pacc += v;
        }
      }
      if (curg >= 0) unsafeAtomicAdd(&gpool[curg * HID + c], pacc);
    }
    if (tid >= 128) {  // stash yy=1 partials; combined below (halves atomics)
      red[tid - 128] = lsum;
      red[tid] = lsq;  // red[128..255]
    }
  }
  __syncthreads();
  if (tid < 128) {
    lsum += red[tid];
    lsq += red[128 + tid];
    unsafeAtomicAdd(&stats[tid], lsum);
    unsafeAtomicAdd(&stats[HID + tid], lsq);
  }
}

// ---------------------------------------------------------------------------
// out[g,c] = scl_c * gpool[g,c] + cnt_g * sh_c  (BN affine commutes with pool)
__device__ __forceinline__ int lbound(const int* __restrict__ arr, int n,
                                      int key) {
  int lo = 0, hi = n;
  while (lo < hi) {
    int mid = (lo + hi) >> 1;
    if (arr[mid] < key) lo = mid + 1; else hi = mid;
  }
  return lo;
}

__global__ __launch_bounds__(128) void finish_kernel(
    const float* __restrict__ gpool, const float* __restrict__ stats,
    const float* __restrict__ gam, const float* __restrict__ bet,
    const int* __restrict__ batch, float* __restrict__ out) {
  __shared__ int cnt_s;
  int g = blockIdx.x, c = threadIdx.x;
  if (c == 0)
    cnt_s = lbound(batch, NNODES, g + 1) - lbound(batch, NNODES, g);
  __syncthreads();
  float mu = stats[c] * (1.0f / NNODES);
  float var = stats[HID + c] * (1.0f / NNODES) - mu * mu;
  float scl = gam[c] * rsqrtf(var + BN_EPS);
  float sh = bet[c] - mu * scl;
  out[g * HID + c] = fmaf(gpool[g * HID + c], scl, (float)cnt_s * sh);
}

// ---------------------------------------------------------------------------
extern "C" void kernel_launch(void* const* d_in, const int* in_sizes, int n_in,
                              void* d_out, int out_size, void* d_ws, size_t ws_size,
                              hipStream_t stream) {
  const int* x_idx = (const int*)d_in[0];
  const int* eidx = (const int*)d_in[1];   // [2, E]: src row then dst row
  const int* eattr = (const int*)d_in[2];
  const int* batch = (const int*)d_in[3];
  const float* node_emb = (const float*)d_in[4];
  const float* edge_emb = (const float*)d_in[5];
  const float* W1 = (const float*)d_in[6];
  const float* b1 = (const float*)d_in[7];
  const float* W2 = (const float*)d_in[8];
  const float* b2 = (const float*)d_in[9];
  const float* bn_g = (const float*)d_in[10];
  const float* bn_b = (const float*)d_in[11];
  float* out = (float*)d_out;

  const size_t nfeat = (size_t)NNODES * HID;
  unsigned short* xbf = (unsigned short*)d_ws;  // [N,H] bf16
  unsigned short* h2bf = xbf + nfeat;           // [N,H] bf16
  float* stats0 = (float*)(h2bf + nfeat);       // [2,H]
  float* stats1 = stats0 + 2 * HID;             // [2,H]
  float* gpool = stats1 + 2 * HID;              // [G,H]
  int* cnt = (int*)(gpool + NGRAPHS * HID);     // [N]   (zeroed with stats)
  int* eout = cnt + NNODES;                     // [N*CAP]
  unsigned short* Wpk = (unsigned short*)(eout + (size_t)NNODES * CAP);
  size_t needed = (size_t)((char*)(Wpk + 131072) - (char*)d_ws);
  if (ws_size < needed) return;  // fails validation loudly, doesn't corrupt

  // zero stats0, stats1, gpool, cnt in one shot (contiguous)
  hipMemsetAsync(stats0, 0, (4 * HID + NGRAPHS * HID + NNODES) * sizeof(int),
                 stream);

  prep_kernel<<<1024, 256, 0, stream>>>(x_idx, node_emb, (unsigned int*)xbf,
                                        eidx, eattr, cnt, eout, W1, W2, Wpk);

  const short8* Wfh = (const short8*)Wpk;  // 8192 frags (hi)
  const short8* Wfl = Wfh + 8192;          // 8192 frags (lo)
  const size_t smem0 = (size_t)NT * LDAF * 4 + 77 * MROW * 4;  // hAp + msgT
  const size_t smem1 = (size_t)NT * LDAF * 4 + 4 * HID * 4;    // hAp + sheL
  // layer 0: in = xbf, msg-table fast path, out -> h2bf, stats0
  gine_mlp_kernel<true><<<GRID_GINE, 512, smem0, stream>>>(
      xbf, nullptr, nullptr, nullptr, cnt, eout, node_emb, edge_emb,
      Wfh + 0 * 2048, Wfl + 0 * 2048, b1, b2, h2bf, stats0, nullptr, nullptr);
  // layer 1: in = h2bf with BN(layer0) folded, out -> gpool + stats1
  gine_mlp_kernel<false><<<GRID_GINE, 512, smem1, stream>>>(
      h2bf, stats0, bn_g, bn_b, cnt, eout, node_emb, edge_emb,
      Wfh + 2 * 2048, Wfl + 2 * 2048, b1 + HID, b2 + HID, nullptr, stats1,
      batch, gpool);
  // final: out = scl*gpool + cnt*sh
  finish_kernel<<<NGRAPHS, 128, 0, stream>>>(gpool, stats1, bn_g + HID,
                                             bn_b + HID, batch, out);
}